// Round 7
// baseline (219.171 us; speedup 1.0000x reference)
//
#include <hip/hip_runtime.h>
#include <math.h>

// Problem constants (fixed by the reference setup_inputs): B=2, P=8192, K=16
#define PP    8192
#define NPTS  16384
#define KNN   16
#define EPSV  1e-17f
#define NCELL 4096           // 16^3 Morton cells per batch
#define NTILE 128            // tiles of 64 sorted points per batch
#define KEY_BIG 3.0e38f      // > any real key, finite

__device__ __forceinline__ int cell_of(float x, float y, float z) {
    int cx = (int)floorf((x + 4.0f) * 2.0f); cx = min(15, max(0, cx));
    int cy = (int)floorf((y + 4.0f) * 2.0f); cy = min(15, max(0, cy));
    int cz = (int)floorf((z + 4.0f) * 2.0f); cz = min(15, max(0, cz));
#define MORT4(v) (((v)&1) | (((v)&2)<<2) | (((v)&4)<<4) | (((v)&8)<<6))
    return MORT4(cx) | (MORT4(cy) << 1) | (MORT4(cz) << 2);
#undef MORT4
}

// sorted-insertion via med3 identity (keys ascending, all >= 0, finite)
__device__ __forceinline__ void insert16(float* keys, float key) {
#pragma unroll
    for (int s = KNN - 1; s >= 1; --s)
        keys[s] = __builtin_amdgcn_fmed3f(keys[s - 1], key, keys[s]);
    keys[0] = fminf(keys[0], key);
}

__device__ __forceinline__ float trunc13(float v) {
    return __uint_as_float(__float_as_uint(v) & 0xFFFFE000u);
}

// ---- K0: fused counting sort + tile AABBs, one block per batch --------------
__global__ __launch_bounds__(1024) void sort_kernel(const float* __restrict__ pts,
                                                    float4* __restrict__ spts4,
                                                    int* __restrict__ sid,
                                                    float4* __restrict__ aabb,
                                                    float* __restrict__ out) {
    __shared__ int h[NCELL];         // histogram, then cursors
    __shared__ int wsum[16];
    const int t = threadIdx.x;
    const int lane = t & 63;
    const int wv = t >> 6;           // 0..15
    const int batch = blockIdx.x;
    const float* bp = pts + (size_t)batch * PP * 3;

    if (batch == 0 && t == 0) out[0] = 0.0f;        // accumulator for K3
    for (int k = t; k < NCELL; k += 1024) h[k] = 0;
    __syncthreads();

    float px[8], py[8], pz[8]; int pc[8];
#pragma unroll
    for (int k = 0; k < 8; ++k) {
        const int p = k * 1024 + t;                  // coalesced
        const float x = bp[p * 3 + 0];
        const float y = bp[p * 3 + 1];
        const float z = bp[p * 3 + 2];
        px[k] = x; py[k] = y; pz[k] = z;
        const int c = cell_of(x, y, z);
        pc[k] = c;
        atomicAdd(&h[c], 1);
    }
    __syncthreads();

    // exclusive scan over 4096 cells: 4/thread + shuffle wave scan + 16-wave scan
    int loc[4]; int s = 0;
#pragma unroll
    for (int k = 0; k < 4; ++k) { loc[k] = s; s += h[t * 4 + k]; }
    int isc = s;
#pragma unroll
    for (int off = 1; off < 64; off <<= 1) {
        const int v = __shfl_up(isc, off, 64);
        if (lane >= off) isc += v;
    }
    if (lane == 63) wsum[wv] = isc;
    __syncthreads();
    if (wv == 0 && lane < 16) {
        const int v = wsum[lane];
        int sc = v;
#pragma unroll
        for (int off = 1; off < 16; off <<= 1) {
            const int u = __shfl_up(sc, off, 16);
            if ((lane & 15) >= off) sc += u;
        }
        wsum[lane] = sc - v;                         // exclusive wave offsets
    }
    __syncthreads();
    const int excl = wsum[wv] + isc - s;
#pragma unroll
    for (int k = 0; k < 4; ++k) h[t * 4 + k] = excl + loc[k];   // cursors
    __syncthreads();

    const int sbase = batch * PP;
#pragma unroll
    for (int k = 0; k < 8; ++k) {
        const int pos = atomicAdd(&h[pc[k]], 1);
        const int p = k * 1024 + t;
        spts4[sbase + pos] = make_float4(px[k], py[k], pz[k],
                                         px[k]*px[k] + py[k]*py[k] + pz[k]*pz[k]);
        sid[sbase + pos] = p;
    }
    __syncthreads();

    // per-tile AABB: wave wv handles tiles wv, wv+16, ... (shuffle reduce)
    for (int t2 = wv; t2 < NTILE; t2 += 16) {
        const float4 c = spts4[sbase + t2 * 64 + lane];
        float lx = c.x, ly = c.y, lz = c.z, hx = c.x, hy = c.y, hz = c.z;
#pragma unroll
        for (int m = 1; m < 64; m <<= 1) {
            lx = fminf(lx, __shfl_xor(lx, m, 64));
            ly = fminf(ly, __shfl_xor(ly, m, 64));
            lz = fminf(lz, __shfl_xor(lz, m, 64));
            hx = fmaxf(hx, __shfl_xor(hx, m, 64));
            hy = fmaxf(hy, __shfl_xor(hy, m, 64));
            hz = fmaxf(hz, __shfl_xor(hz, m, 64));
        }
        if (lane == 0) {
            aabb[(batch * NTILE + t2) * 2 + 0] = make_float4(lx, ly, lz, 0.f);
            aabb[(batch * NTILE + t2) * 2 + 1] = make_float4(hx, hy, hz, 0.f);
        }
    }
}

// ---- K1: best-first exact 16-NN + fused phi/denoise1 ------------------------
// 256 blocks x 512. Block = 64 queries (sorted tile t_q), 8 waves.
// Tiles bucketed by box-box dist to t_q (16 buckets, width 1/8). Scan buckets
// ascending, 8 tiles (512 cands) per staged batch; block-wide break when
// trunc(bucket_edge^2) >= keys[15] for every lane of every wave (exact:
// q in box(t_q) => point-to-box >= box-box >= edge). Per-tile per-wave
// ballot skip on point-to-box. Key/dist math verbatim from absmax-0 rounds.
__global__ __launch_bounds__(512) void knn_kernel(const float* __restrict__ pts,
                                                  const float* __restrict__ normals,
                                                  const float4* __restrict__ spts4,
                                                  const int* __restrict__ sid,
                                                  const float4* __restrict__ aabb,
                                                  int* __restrict__ out_idx,
                                                  float* __restrict__ out_dist,
                                                  float* __restrict__ phi_out,
                                                  float* __restrict__ n1_out) {
    __shared__ float4 lds_aabb[2 * NTILE];           // 4 KB
    __shared__ float4 batF[512];                     // 8 KB
    __shared__ int    batI[512];                     // 2 KB
    __shared__ float  smerge[8 * KNN * 64];          // 32 KB
    __shared__ int    bcnt[16];
    __shared__ short  border[NTILE];                 // bucket-ordered tile list
    __shared__ short  bband[NTILE];                  // bucket index per position
    __shared__ int    anyopen;

    const int tid   = threadIdx.x;
    const int lane  = tid & 63;
    const int wave  = tid >> 6;
    const int batch = blockIdx.x >> 7;
    const int t_q   = blockIdx.x & (NTILE - 1);
    const int sbase = batch * PP;

    if (tid < 2 * NTILE) lds_aabb[tid] = aabb[batch * 2 * NTILE + tid];
    if (tid < 16) bcnt[tid] = 0;
    // per-lane query (issued early; global, L2-resident)
    const float4 q4  = spts4[sbase + t_q * 64 + lane];
    const int    qid = sid  [sbase + t_q * 64 + lane];
    __syncthreads();

    // bucket the 128 tiles by box-box distance to t_q
    int myb = 0;
    if (tid < NTILE) {
        const float4 qlo = lds_aabb[2 * t_q + 0];
        const float4 qhi = lds_aabb[2 * t_q + 1];
        const float4 lo  = lds_aabb[2 * tid + 0];
        const float4 hi  = lds_aabb[2 * tid + 1];
        const float gx = fmaxf(fmaxf(lo.x - qhi.x, qlo.x - hi.x), 0.0f);
        const float gy = fmaxf(fmaxf(lo.y - qhi.y, qlo.y - hi.y), 0.0f);
        const float gz = fmaxf(fmaxf(lo.z - qhi.z, qlo.z - hi.z), 0.0f);
        const float d2 = gx * gx + gy * gy + gz * gz;
        myb = min(15, (int)(sqrtf(d2) * 8.0f));
        atomicAdd(&bcnt[myb], 1);
    }
    __syncthreads();
    if (tid == 0) { int s = 0; for (int i = 0; i < 16; ++i) { const int c = bcnt[i]; bcnt[i] = s; s += c; } }
    __syncthreads();
    if (tid < NTILE) {
        const int pos = atomicAdd(&bcnt[myb], 1);
        border[pos] = (short)tid;
        bband[pos]  = (short)myb;
    }
    __syncthreads();

    const float qx = q4.x, qy = q4.y, qz = q4.z, d2q = q4.w;
    float keys[KNN];
#pragma unroll
    for (int s = 0; s < KNN; ++s) keys[s] = KEY_BIG;

    // best-first batched scan with block-wide break
    for (int base = 0; base < NTILE; base += 8) {
        const float lbd = (float)bband[base] * 0.125f;   // bucket lower edge
        const float lbk = trunc13(lbd * lbd);            // lower bound in key space
        if (tid == 0) anyopen = 0;
        __syncthreads();                                 // also fences prev batch reads
        { const unsigned long long bal = __ballot(lbk < keys[KNN - 1]);
          if (lane == 0 && bal != 0ull) anyopen = 1; }
        __syncthreads();
        if (anyopen == 0) break;                         // exact: see header comment

        const int rem = min(8, NTILE - base);
        if (wave < rem) {                                // stage 8 tiles, coalesced
            const int tt = border[base + wave];
            batF[tid] = spts4[sbase + tt * 64 + lane];
            batI[tid] = sid  [sbase + tt * 64 + lane];
        }
        __syncthreads();
        for (int r = 0; r < rem; ++r) {                  // per-tile adaptive skip
            const int tt = border[base + r];
            const float4 lo = lds_aabb[2 * tt + 0];
            const float4 hi = lds_aabb[2 * tt + 1];
            const float ax = fmaxf(fmaxf(lo.x - qx, qx - hi.x), 0.0f);
            const float ay = fmaxf(fmaxf(lo.y - qy, qy - hi.y), 0.0f);
            const float az = fmaxf(fmaxf(lo.z - qz, qz - hi.z), 0.0f);
            const float bd = ax * ax + ay * ay + az * az;
            if (__ballot(trunc13(bd) < keys[KNN - 1]) == 0ull) continue;
#pragma unroll
            for (int k = 0; k < 8; ++k) {
                const int jj = r * 64 + wave + 8 * k;
                const float4 c4 = batF[jj];              // LDS broadcast
                const int sj = batI[jj];
                const float dot = __builtin_fmaf(qz, c4.z,
                                  __builtin_fmaf(qy, c4.y, qx * c4.x));
                const float d = __builtin_fmaf(-2.0f, dot, d2q + c4.w);
                const float dc = fmaxf(d, 0.0f);
                unsigned int kb = (__float_as_uint(dc) & 0xFFFFE000u) | (unsigned int)sj;
                float key = __uint_as_float(kb);
                if (sj == qid) key = KEY_BIG;            // exclude self
                insert16(keys, key);
            }
        }
    }

    // tree merge of 8 per-wave top-16s (3 rounds)
    __syncthreads();
#pragma unroll
    for (int s = 0; s < KNN; ++s) smerge[(wave * KNN + s) * 64 + lane] = keys[s];
    for (int step = 1; step < 8; step <<= 1) {
        __syncthreads();
        if ((wave & (2 * step - 1)) == 0) {
            const int partner = wave + step;
#pragma unroll
            for (int s2 = 0; s2 < KNN; ++s2)
                insert16(keys, smerge[(partner * KNN + s2) * 64 + lane]);
            if (wave != 0) {
#pragma unroll
                for (int s = 0; s < KNN; ++s) smerge[(wave * KNN + s) * 64 + lane] = keys[s];
            }
        }
    }

    if (wave == 0) {   // epilogue: exact dists, idx, phi, n1 (verbatim semantics)
        const float* bp = pts + (size_t)batch * PP * 3;
        const float* bn = normals + (size_t)batch * PP * 3;
        const int qrow = batch * PP + qid;
        float d[KNN]; int jidx[KNN];
#pragma unroll
        for (int s = 0; s < KNN; ++s) {
            const int j = (int)(__float_as_uint(keys[s]) & 0x1FFFu);
            jidx[s] = j;
            out_idx[qrow * KNN + s] = j;
            const float x = bp[j * 3 + 0];
            const float y = bp[j * 3 + 1];
            const float z = bp[j * 3 + 2];
            const float dot = qx * x + qy * y + qz * z;
            const float dd = (d2q + (x * x + y * y + z * z)) - (dot + dot);
            const float dcl = fmaxf(dd, 0.0f);
            out_dist[qrow * KNN + s] = dcl;
            d[s] = dcl;
        }
        float d1 = d[0];
#pragma unroll
        for (int s = 1; s < KNN; ++s) d1 = fminf(d1, d[s]);
        const float s0 = d1 * 8.0f;                  // 2 * FILTER_SCALE^2
        const float sden = (s0 < EPSV) ? EPSV : s0;
        float sphi = 0.f, nx = 0.f, ny = 0.f, nz = 0.f;
#pragma unroll
        for (int s = 0; s < KNN; ++s) {
            const float w = fmaxf(1.0f - d[s] / sden, 0.0f);
            const float w2 = w * w;
            const float ph = w2 * w2;
            phi_out[qrow * KNN + s] = ph;
            const int j = jidx[s];
            nx += ph * bn[j * 3 + 0];
            ny += ph * bn[j * 3 + 1];
            nz += ph * bn[j * 3 + 2];
            sphi += ph;
        }
        const float den = (sphi < EPSV) ? EPSV : sphi;
        n1_out[qrow * 3 + 0] = nx / den;
        n1_out[qrow * 3 + 1] = ny / den;
        n1_out[qrow * 3 + 2] = nz / den;
    }
}

// ---- K2: normal_w + second denoise (n2), one thread per query ---------------
__global__ __launch_bounds__(256) void denoise2_kernel(const int* __restrict__ idx,
                                const float* __restrict__ phi,
                                const float* __restrict__ n1,
                                float* __restrict__ nw_out,
                                float* __restrict__ n2_out) {
    const int q = blockIdx.x * blockDim.x + threadIdx.x;
    if (q >= NPTS) return;
    const int b = q >> 13;
    const int gbase = b * PP;
    const float INV_SIG = 1.0f / (0.75f * 0.75f);

    const float ax = n1[q * 3 + 0];
    const float ay = n1[q * 3 + 1];
    const float az = n1[q * 3 + 2];
    const float an = fmaxf(sqrtf(ax * ax + ay * ay + az * az), 1e-12f);
    const float rx = ax / an, ry = ay / an, rz = az / an;

    float swn = 0.f, ox = 0.f, oy = 0.f, oz = 0.f;
#pragma unroll
    for (int s = 0; s < KNN; ++s) {
        const int j = idx[q * KNN + s];
        const float bx = n1[(gbase + j) * 3 + 0];
        const float by = n1[(gbase + j) * 3 + 1];
        const float bz = n1[(gbase + j) * 3 + 2];
        const float bnn = fmaxf(sqrtf(bx * bx + by * by + bz * bz), 1e-12f);
        const float ux = bx / bnn - rx;
        const float uy = by / bnn - ry;
        const float uz = bz / bnn - rz;
        const float dd = ux * ux + uy * uy + uz * uz;
        const float nw = expf(-dd * INV_SIG);
        nw_out[q * KNN + s] = nw;
        const float wk = phi[q * KNN + s] * nw;
        ox += wk * bx;
        oy += wk * by;
        oz += wk * bz;
        swn += wk;
    }
    const float den = (swn < EPSV) ? EPSV : swn;
    n2_out[q * 3 + 0] = ox / den;
    n2_out[q * 3 + 1] = oy / den;
    n2_out[q * 3 + 2] = oz / den;
}

// ---- K3: loss, one thread per (q, neighbor), atomic mean --------------------
__global__ __launch_bounds__(256) void loss_kernel(const float* __restrict__ pts,
                                                   const int* __restrict__ idx,
                                                   const float* __restrict__ dist,
                                                   const float* __restrict__ phi,
                                                   const float* __restrict__ nw,
                                                   const float* __restrict__ n2,
                                                   float* __restrict__ out) {
    __shared__ float red[4];
    const int g = blockIdx.x * 256 + threadIdx.x;    // 0 .. 262143
    const int q = g >> 4;
    const int b = q >> 13;
    const int il = q & (PP - 1);
    const int gbase = b * PP;
    const float* bp = pts + (size_t)b * PP * 3;

    const float dj = dist[g];
    float d1 = dj;
#pragma unroll
    for (int m = 1; m < 16; m <<= 1) d1 = fminf(d1, __shfl_xor(d1, m, 16));
    const float thresh = 4.0f * d1;                  // FILTER_SCALE * d1 * 2

    float w = phi[g] * nw[g];
    if (dj > thresh) w = 0.f;                        // ball-query mask

    const int jj = idx[g];
    const float n2x = n2[(gbase + jj) * 3 + 0];
    const float n2y = n2[(gbase + jj) * 3 + 1];
    const float n2z = n2[(gbase + jj) * 3 + 2];
    const float dts = (bp[jj * 3 + 0] - bp[il * 3 + 0]) * n2x +
                      (bp[jj * 3 + 1] - bp[il * 3 + 1]) * n2y +
                      (bp[jj * 3 + 2] - bp[il * 3 + 2]) * n2z;
    float num = dts * dts * w;
    float den = w;
#pragma unroll
    for (int m = 1; m < 16; m <<= 1) {
        num += __shfl_xor(num, m, 16);
        den += __shfl_xor(den, m, 16);
    }
    const float ddv = (den < EPSV) ? EPSV : den;
    float v = num / ddv;                             // identical across 16 lanes
    v += __shfl_xor(v, 16, 64);
    v += __shfl_xor(v, 32, 64);                      // sum of wave's 4 q-groups
    if ((threadIdx.x & 63) == 0) red[threadIdx.x >> 6] = v;
    __syncthreads();
    if (threadIdx.x == 0)
        atomicAdd(out, (red[0] + red[1] + red[2] + red[3]) * (1.0f / (float)NPTS));
}

// ---- launch -----------------------------------------------------------------
extern "C" void kernel_launch(void* const* d_in, const int* in_sizes, int n_in,
                              void* d_out, int out_size, void* d_ws, size_t ws_size,
                              hipStream_t stream) {
    const float* points  = (const float*)d_in[0];   // (2, 8192, 3) f32
    const float* normals = (const float*)d_in[1];   // (2, 8192, 3) f32
    float* out = (float*)d_out;                     // scalar f32

    // workspace (floats): idx @0 | dist @262144 | phi @524288 |
    // nw @786432 (overlaps sort scratch: spts4 @786432, sid @851968, aabb @868352
    //             -- dead before denoise2 writes nw) | n1 @1048576 | n2 @1097728
    float* wsf      = (float*)d_ws;
    int*    w_idx   = (int*)wsf;                     // 262144 ints
    float*  w_dist  = wsf + 262144;
    float*  w_phi   = wsf + 524288;
    float*  w_nw    = wsf + 786432;
    float4* w_spts  = (float4*)(wsf + 786432);       // 16384 float4
    int*    w_sid   = (int*)(wsf + 851968);          // 16384 ints
    float4* w_aabb  = (float4*)(wsf + 868352);       // 512 float4
    float*  w_n1    = wsf + 1048576;                 // 49152
    float*  w_n2    = wsf + 1097728;                 // 49152

    sort_kernel<<<2, 1024, 0, stream>>>(points, w_spts, w_sid, w_aabb, out);
    knn_kernel<<<256, 512, 0, stream>>>(points, normals, w_spts, w_sid, w_aabb,
                                        w_idx, w_dist, w_phi, w_n1);
    denoise2_kernel<<<NPTS / 256, 256, 0, stream>>>(w_idx, w_phi, w_n1, w_nw, w_n2);
    loss_kernel<<<NPTS * KNN / 256, 256, 0, stream>>>(points, w_idx, w_dist, w_phi,
                                                      w_nw, w_n2, out);
}